// Round 3
// 306.514 us; speedup vs baseline: 1.0246x; 1.0246x over previous
//
#include <hip/hip_runtime.h>

// MultiHeadedAttention B=8,S=1024,D=1024,H=16,dk=64 — bf16 MFMA pipeline.
// R7: fixes R6's staging/consumption mismatch. Staging groups are now the
// exact per-phase consumption sets (uniform across waves):
//   A-p1 = rows {0..63}u{128..191}   A-p2 = rows {64..127}u{192..255}
//   B-p1 = rows {0..31,64..95,128..159,192..223}   B-p2 = +32
// so the counted-vmcnt ledger (vmcnt(4) at ph1/ph2/ph4; 4->2->0 drain in the
// peeled last tile) guarantees exactly the rows each phase ds_reads.
// Everything else (XOR swizzle both-sides, setprio, XCD swizzle, static
// 128 KiB LDS, attention) unchanged from R6.

#define Sdim 1024
#define Ddim 1024

typedef unsigned short u16;
typedef float f32x4 __attribute__((ext_vector_type(4)));
typedef float f32x16 __attribute__((ext_vector_type(16)));
typedef __bf16 bf16x8 __attribute__((ext_vector_type(8)));
typedef u16 u16x8 __attribute__((ext_vector_type(8)));
typedef __attribute__((address_space(3))) void lds_void;
typedef __attribute__((address_space(1))) void gbl_void;

__device__ __forceinline__ u16 f2bf(float f) {
    unsigned u = __float_as_uint(f);
    u += 0x7fffu + ((u >> 16) & 1u);   // RNE
    return (u16)(u >> 16);
}
__device__ __forceinline__ void gld16(const void* g, void* l) {
    __builtin_amdgcn_global_load_lds((const gbl_void*)g, (lds_void*)l, 16, 0, 0);
}
// pack two f32 -> two bf16 (round-half-up) in one u32 via v_perm
__device__ __forceinline__ unsigned pk_bf16(float lo, float hi) {
    const unsigned ul = __float_as_uint(lo) + 0x8000u;
    const unsigned uh = __float_as_uint(hi) + 0x8000u;
    return __builtin_amdgcn_perm(uh, ul, 0x07060302u);
}
#define MFMA16(a, b, c) __builtin_amdgcn_mfma_f32_16x16x32_bf16((a), (b), (c), 0, 0, 0)
#define MFMA32(a, b, c) __builtin_amdgcn_mfma_f32_32x32x16_bf16((a), (b), (c), 0, 0, 0)

#define WAITVM(n) asm volatile("s_waitcnt vmcnt(" #n ")" ::: "memory")
#define WAITLGKM0 asm volatile("s_waitcnt lgkmcnt(0)" ::: "memory")
#define SBAR() __builtin_amdgcn_s_barrier()
#define SCHEDB() __builtin_amdgcn_sched_barrier(0)

// ---------------------------------------------------------------------------
// fused fp32->bf16 converts; y=0..2 activations (8M), y=3..6 weights (1M).
// y==3 (wq) is scaled by 0.125 (folds the 1/sqrt(dk) into Q projection).
// ---------------------------------------------------------------------------
__global__ __launch_bounds__(256) void cvt_all(const float* __restrict__ s0,
                                               const float* __restrict__ s1,
                                               const float* __restrict__ s2,
                                               const float* __restrict__ s3,
                                               const float* __restrict__ s4,
                                               const float* __restrict__ s5,
                                               const float* __restrict__ s6,
                                               u16* __restrict__ d0, u16* __restrict__ d1,
                                               u16* __restrict__ d2, u16* __restrict__ d3,
                                               u16* __restrict__ d4, u16* __restrict__ d5,
                                               u16* __restrict__ d6) {
    const int z = blockIdx.y;
    if (z >= 3 && blockIdx.x >= 512) return;
    const float* s = z == 0 ? s0 : z == 1 ? s1 : z == 2 ? s2 : z == 3 ? s3
                   : z == 4 ? s4 : z == 5 ? s5 : s6;
    u16* d = z == 0 ? d0 : z == 1 ? d1 : z == 2 ? d2 : z == 3 ? d3
           : z == 4 ? d4 : z == 5 ? d5 : d6;
    const float sc = (z == 3) ? 0.125f : 1.0f;
    const int i = (blockIdx.x * 256 + threadIdx.x) * 8;
    const float4 a = *(const float4*)(s + i);
    const float4 b = *(const float4*)(s + i + 4);
    u16x8 o;
    o[0] = f2bf(a.x * sc); o[1] = f2bf(a.y * sc); o[2] = f2bf(a.z * sc); o[3] = f2bf(a.w * sc);
    o[4] = f2bf(b.x * sc); o[5] = f2bf(b.y * sc); o[6] = f2bf(b.z * sc); o[7] = f2bf(b.w * sc);
    *(u16x8*)(d + i) = o;
}

// ---------------------------------------------------------------------------
// 256x256 8-phase GEMM: C[M][1024] = A[M][1024] @ W[1024][1024]^T + bias*bscale
// 512 threads = 8 waves (2 row x 4 col); per-wave 128x64 output; BK=64.
// LDS (static 128 KiB): As[2][256][64] @0, Bs[2][256][64] @65536 (bytes).
// LDS row r == global row r; within-row chunk c (16B) holds global chunk
// c ^ (r&7) — XOR swizzle applied on ds_read addr and inverted on the global
// source of global_load_lds (linear LDS dest — rule 21).
// Staging groups == phase consumption sets (see header). FIFO issue order
// A-p1,B-p1,B-p2,A-p2; counted vmcnt(4) in steady state; drain 4->2->0 only
// in the peeled final tile.
// ---------------------------------------------------------------------------
__device__ __forceinline__ void mfma_block(f32x4 (&acc)[8][4], const bf16x8 (&Af)[4][2],
                                           const bf16x8 (&Bf)[2][2], int mb, int nb) {
#pragma unroll
    for (int mi = 0; mi < 4; ++mi)
#pragma unroll
        for (int ni = 0; ni < 2; ++ni) {
            f32x4 c = acc[mb + mi][nb + ni];
            c = MFMA16(Af[mi][0], Bf[ni][0], c);
            c = MFMA16(Af[mi][1], Bf[ni][1], c);
            acc[mb + mi][nb + ni] = c;
        }
}

template <bool OUT_BF16>
__device__ __forceinline__ void gemm8_body(const u16* __restrict__ A,
                                           const u16* __restrict__ W,
                                           const float* __restrict__ bias, float bscale,
                                           void* __restrict__ Cout,
                                           char* __restrict__ smem,
                                           int m0, int n0) {
    const int tid  = threadIdx.x;
    const int w    = tid >> 6;
    const int lane = tid & 63;
    const int l15  = lane & 15;
    const int quad = lane >> 4;
    const int wr   = w >> 2;          // 0..1 : 128-row block
    const int wc   = w & 3;           // 0..3 : 64-col block

    // ---- staging addressing: per-lane global src (inverse-swizzled cols),
    //      wave-uniform linear LDS dest (+lane*16 by HW) ----
    const int srA = w * 8 + (lane >> 3);                          // A: rows 0..63
    const int srB = (w & 3) * 8 + (w >> 2) * 64 + (lane >> 3);    // B: 0..31,64..95
    const int scol = (((lane & 7) ^ ((lane >> 3) & 7)) << 3);     // u16 units
    const u16* pa = A + (size_t)(m0 + srA) * Ddim + scol;
    const u16* pb = W + (size_t)(n0 + srB) * Ddim + scol;
    char* sA = smem + w * 1024;
    char* sB = smem + 65536 + (w & 3) * 1024 + (w >> 2) * 8192;

// A-p1 (h=0): rows {0..63}u{128..191}; A-p2 (h=1): rows {64..127}u{192..255}
#define STG_A(h, kk, b)                                                          \
    do {                                                                         \
        gld16(pa + (size_t)(h) * 65536 + (kk) * 64,                              \
              sA + (b) * 32768 + (h) * 8192);                                    \
        gld16(pa + (size_t)(h) * 65536 + 131072 + (kk) * 64,                     \
              sA + (b) * 32768 + (h) * 8192 + 16384);                            \
    } while (0)
// B-p1 (h=0): rows {0..31,64..95}u{128..159,192..223}; B-p2 (h=1): +32 rows
#define STG_B(h, kk, b)                                                          \
    do {                                                                         \
        gld16(pb + (size_t)(h) * 32768 + (kk) * 64,                              \
              sB + (b) * 32768 + (h) * 4096);                                    \
        gld16(pb + (size_t)(h) * 32768 + 131072 + (kk) * 64,                     \
              sB + (b) * 32768 + (h) * 4096 + 16384);                            \
    } while (0)

    // ---- fragment read addressing (swizzled) ----
    const char* Ab = smem + (size_t)(wr * 128 + l15) * 128;
    const char* Bb = smem + 65536 + (size_t)(wc * 64 + l15) * 128;
    const int cx = ((quad ^ (l15 & 7)) << 4);   // ks=0 col-byte; ks=1 is cx^64

    f32x4 acc[8][4] = {};
    bf16x8 Af[4][2], Bf0[2][2], Bf1[2][2];

    // ---- prologue: K-tile 0 into buf0, FIFO order A-p1,B-p1,B-p2,A-p2 ----
    STG_A(0, 0, 0);
    STG_B(0, 0, 0);
    STG_B(1, 0, 0);
    STG_A(1, 0, 0);
    WAITVM(4);        // A-p1,B-p1 landed (B-p2,A-p2 may be in flight)
    SBAR();

    for (int t = 0; t < 16; ++t) {
        const int bo = (t & 1) * 32768;
        const int nb = 1 - (t & 1);
        const bool pf = (t < 15);
        // ===== phase 1: read A rows wr*128+[0..63] + B rows wc*64+[0..31];
        //               MFMA quadrant (0,0) =====
#pragma unroll
        for (int mi = 0; mi < 4; ++mi) {
            Af[mi][0] = *(const bf16x8*)(Ab + bo + mi * 2048 + cx);
            Af[mi][1] = *(const bf16x8*)(Ab + bo + mi * 2048 + (cx ^ 64));
        }
#pragma unroll
        for (int ni = 0; ni < 2; ++ni) {
            Bf0[ni][0] = *(const bf16x8*)(Bb + bo + ni * 2048 + cx);
            Bf0[ni][1] = *(const bf16x8*)(Bb + bo + ni * 2048 + (cx ^ 64));
        }
        if (pf) STG_A(0, t + 1, nb);
        SCHEDB();
        if (pf) { WAITVM(4); } else { WAITVM(2); }   // B-p2[t] landed
        SBAR();
        WAITLGKM0;
        SCHEDB();
        __builtin_amdgcn_s_setprio(1);
        mfma_block(acc, Af, Bf0, 0, 0);
        __builtin_amdgcn_s_setprio(0);
        SBAR();
        // ===== phase 2: read B rows wc*64+[32..63]; MFMA quadrant (0,1) =====
#pragma unroll
        for (int ni = 0; ni < 2; ++ni) {
            Bf1[ni][0] = *(const bf16x8*)(Bb + bo + (2 + ni) * 2048 + cx);
            Bf1[ni][1] = *(const bf16x8*)(Bb + bo + (2 + ni) * 2048 + (cx ^ 64));
        }
        if (pf) STG_B(0, t + 1, nb);
        SCHEDB();
        if (pf) { WAITVM(4); } else { WAITVM(0); }   // A-p2[t] landed
        SBAR();
        WAITLGKM0;
        SCHEDB();
        __builtin_amdgcn_s_setprio(1);
        mfma_block(acc, Af, Bf1, 0, 2);
        __builtin_amdgcn_s_setprio(0);
        SBAR();
        // ===== phase 3: read A rows wr*128+[64..127]; MFMA quadrant (1,0) =====
#pragma unroll
        for (int mi = 0; mi < 4; ++mi) {
            Af[mi][0] = *(const bf16x8*)(Ab + bo + (4 + mi) * 2048 + cx);
            Af[mi][1] = *(const bf16x8*)(Ab + bo + (4 + mi) * 2048 + (cx ^ 64));
        }
        if (pf) STG_B(1, t + 1, nb);
        SCHEDB();
        SBAR();
        WAITLGKM0;
        SCHEDB();
        __builtin_amdgcn_s_setprio(1);
        mfma_block(acc, Af, Bf0, 4, 0);
        __builtin_amdgcn_s_setprio(0);
        SBAR();
        // ===== phase 4: MFMA quadrant (1,1) =====
        if (pf) STG_A(1, t + 1, nb);
        SCHEDB();
        if (pf) { WAITVM(4); }   // A-p1,B-p1 of t+1 landed for next ph1
        SBAR();
        SCHEDB();
        __builtin_amdgcn_s_setprio(1);
        mfma_block(acc, Af, Bf1, 4, 2);
        __builtin_amdgcn_s_setprio(0);
        SBAR();
    }
#undef STG_A
#undef STG_B

    // ---- epilogue ----
    float bv[4];
#pragma unroll
    for (int ni = 0; ni < 4; ++ni)
        bv[ni] = bias[n0 + wc * 64 + ni * 16 + l15] * bscale;
#pragma unroll
    for (int mi = 0; mi < 8; ++mi)
#pragma unroll
        for (int ni = 0; ni < 4; ++ni)
#pragma unroll
            for (int r = 0; r < 4; ++r) {
                const int row = m0 + wr * 128 + mi * 16 + quad * 4 + r;
                const int col = n0 + wc * 64 + ni * 16 + l15;
                const float v = acc[mi][ni][r] + bv[ni];
                if (OUT_BF16)
                    ((u16*)Cout)[(size_t)row * Ddim + col] = f2bf(v);
                else
                    ((float*)Cout)[(size_t)row * Ddim + col] = v;
            }
}

__global__ __launch_bounds__(512, 2) void gemm8_qkv(
        const u16* __restrict__ A0, const u16* __restrict__ A1, const u16* __restrict__ A2,
        const u16* __restrict__ W0, const u16* __restrict__ W1, const u16* __restrict__ W2,
        const float* __restrict__ b0, const float* __restrict__ b1, const float* __restrict__ b2,
        u16* __restrict__ C0, u16* __restrict__ C1, u16* __restrict__ C2) {
    __shared__ __align__(16) char smem[131072];
    // bijective XCD swizzle over 384 WGs (384 % 8 == 0 -> simple form valid)
    const int d = blockIdx.x + (blockIdx.y << 2) + (blockIdx.z << 7);
    const int s = (d & 7) * 48 + (d >> 3);
    const int z = s >> 7;
    const int rr = s & 127;
    const int tm = rr >> 2, tn = rr & 3;
    const u16* A = z == 0 ? A0 : z == 1 ? A1 : A2;
    const u16* W = z == 0 ? W0 : z == 1 ? W1 : W2;
    const float* bias = z == 0 ? b0 : z == 1 ? b1 : b2;
    u16* C = z == 0 ? C0 : z == 1 ? C1 : C2;
    const float bsc = (z == 0) ? 0.125f : 1.0f;   // wq path is pre-scaled
    gemm8_body<true>(A, W, bias, bsc, (void*)C, smem, tm * 256, tn * 256);
}

__global__ __launch_bounds__(512, 2) void gemm8_dense(const u16* __restrict__ A,
                                                      const u16* __restrict__ W,
                                                      const float* __restrict__ bias,
                                                      float* __restrict__ C) {
    __shared__ __align__(16) char smem[131072];
    const int d = blockIdx.x + (blockIdx.y << 2);       // 128 WGs
    const int s = (d & 7) * 16 + (d >> 3);
    const int tm = s >> 2, tn = s & 3;
    gemm8_body<false>(A, W, bias, 1.0f, (void*)C, smem, tm * 256, tn * 256);
}

// ---------------------------------------------------------------------------
// V transpose: Vp[B*S][D] (bf16) -> Vt_g[(b*16+h)*64 + d][S]
// ---------------------------------------------------------------------------
__global__ __launch_bounds__(256) void transp_v(const u16* __restrict__ Vp,
                                                u16* __restrict__ Vt) {
    __shared__ __align__(16) u16 Ts[64][72];
    const int bh = blockIdx.x, s0 = blockIdx.y * 64;
    const int b = bh >> 4, h = bh & 15;
    const int tid = threadIdx.x;
#pragma unroll
    for (int p = 0; p < 2; ++p) {
        const int e = p * 2048 + tid * 8;
        const int r = e >> 6, c = e & 63;
        *(u16x8*)&Ts[r][c] =
            *(const u16x8*)(Vp + ((size_t)(b * Sdim + s0 + r)) * Ddim + h * 64 + c);
    }
    __syncthreads();
    const int d = tid >> 2, sp = tid & 3;
#pragma unroll
    for (int g = 0; g < 2; ++g) {
        u16x8 o;
#pragma unroll
        for (int j = 0; j < 8; ++j) o[j] = Ts[sp * 16 + g * 8 + j][d];
        *(u16x8*)(Vt + ((size_t)(bh * 64 + d)) * Sdim + s0 + sp * 16 + g * 8) = o;
    }
}

// ---------------------------------------------------------------------------
// Attention on 32x32 MFMA. Block = 256 q-rows of one (b,h); wave owns 64 q.
// Per 64-kpos tile: S^T = K.Q^T (A=K-frag, B=Q-frag cached in regs);
// p = exp(s)*pol in f32; P regs re-laid C->A via shfl_xor(32)+cndmask;
// X += P.V^T. All LDS tiles stride 72 u16 (conflict-free for 32-row frags).
// ---------------------------------------------------------------------------
__global__ __launch_bounds__(256, 2) void attn_mfma(const u16* __restrict__ Qp,
                                                    const u16* __restrict__ Kp,
                                                    const u16* __restrict__ Vt,
                                                    const float* __restrict__ pol,
                                                    u16* __restrict__ Xb) {
    __shared__ __align__(16) u16 lds[28288];    // 56576 B
    u16* Qs = lds;                              // 256 x 72  (later: Xout)
    u16* Ks = lds + 18432;                      // 64 x 72   K[kpos][dk]
    u16* Vs = lds + 23040;                      // 64 x 72   V^T[d][kpos]
    float* pols = (float*)(lds + 27648);        // [64]
    float* denb = pols + 64;                    // [256] inv-den

    const int tid  = threadIdx.x;
    const int w    = tid >> 6;
    const int lane = tid & 63;
    const int l31  = lane & 31;
    const unsigned hsel = lane >> 5;            // half selector
    const int q0 = blockIdx.x * 256;
    const int bh = blockIdx.y;
    const size_t bS = (size_t)(bh >> 4) * Sdim;
    const int col0 = (bh & 15) * 64;
    const int sr = tid >> 2;                    // staging row 0..63
    const int sc4 = tid & 3;                    // staging chunk base

    // ---- stage Q tile 256x64 and load Q B-frags into registers ----
#pragma unroll
    for (int rg = 0; rg < 4; ++rg) {
        const int r = rg * 64 + sr;
#pragma unroll
        for (int g = 0; g < 2; ++g) {
            const int ch = sc4 + g * 4;
            *(u16x8*)(Qs + r * 72 + ch * 8) =
                *(const u16x8*)(Qp + (bS + q0 + r) * Ddim + col0 + ch * 8);
        }
    }
    __syncthreads();
    bf16x8 Qf[2][4];
#pragma unroll
    for (int qt = 0; qt < 2; ++qt)
#pragma unroll
        for (int dkt = 0; dkt < 4; ++dkt)
            Qf[qt][dkt] = *(const bf16x8*)(Qs + (w * 64 + qt * 32 + l31) * 72 +
                                           dkt * 16 + hsel * 8);

    f32x16 X[2][2] = {};
    float den[2] = {0.f, 0.f};

    for (int kt = 0; kt < 16; ++kt) {
        const int kbase = kt * 64;
        __syncthreads();
        // stage K[64][64] and V^T[64][64]
#pragma unroll
        for (int g = 0; g < 2; ++g) {
            const int ch = sc4 + g * 4;
            *(u16x8*)(Ks + sr * 72 + ch * 8) =
                *(const u16x8*)(Kp + (bS + kbase + sr) * Ddim + col0 + ch * 8);
            *(u16x8*)(Vs + sr * 72 + ch * 8) =
                *(const u16x8*)(Vt + ((size_t)(bh * 64 + sr)) * Sdim + kbase + ch * 8);
        }
        if (tid < 64) pols[tid] = pol[bS + kbase + tid];
        __syncthreads();

#pragma unroll
        for (int t32 = 0; t32 < 2; ++t32) {
            // pol per C-layout row (broadcast reads; uniform per (e,half))
            float polv[16];
#pragma unroll
            for (int e = 0; e < 16; ++e)
                polv[e] = pols[t32 * 32 + (e & 3) + 8 * (e >> 2) + 4 * hsel];
            bf16x8 Kf[4];
#pragma unroll
            for (int dkt = 0; dkt < 4; ++dkt)
                Kf[dkt] = *(const bf16x8*)(Ks + (t32 * 32 + l31) * 72 +
                                           dkt * 16 + hsel * 8);
#pragma unroll
            for (int qt = 0; qt < 2; ++qt) {
                f32x16 S = {};
#pragma unroll
                for (int dkt = 0; dkt < 4; ++dkt)
                    S = MFMA32(Kf[dkt], Qf[qt][dkt], S);   // D[kpos][q]
                // softmax numerator (f32), accumulate den per-lane (q = l31)
                float p[16];
#pragma unroll
                for (int e = 0; e < 16; ++e) {
                    p[e] = __expf(S[e]) * polv[e];
                    den[qt] += p[e];
                }
                // pack pairs along kpos rows: pk_[2g]=(c0,c1), pk_[2g+1]=(c2,c3)
                unsigned pk_[8], sw[8];
#pragma unroll
                for (int g = 0; g < 4; ++g) {
                    pk_[2 * g]     = pk_bf16(p[4 * g + 0], p[4 * g + 1]);
                    pk_[2 * g + 1] = pk_bf16(p[4 * g + 2], p[4 * g + 3]);
                }
#pragma unroll
                for (int i = 0; i < 8; ++i)
                    sw[i] = (unsigned)__shfl_xor((int)pk_[i], 32);
                // P A-frags for the two 16-k tiles of this 32-kpos block
#pragma unroll
                for (int tau = 0; tau < 2; ++tau) {
                    union { unsigned u[4]; bf16x8 v; } Af;
                    Af.u[0] = hsel ? sw[(2 * tau + 1) * 2 + 0] : pk_[(2 * tau) * 2 + 0];
                    Af.u[1] = hsel ? sw[(2 * tau + 1) * 2 + 1] : pk_[(2 * tau) * 2 + 1];
                    Af.u[2] = hsel ? pk_[(2 * tau + 1) * 2 + 0] : sw[(2 * tau) * 2 + 0];
                    Af.u[3] = hsel ? pk_[(2 * tau + 1) * 2 + 1] : sw[(2 * tau) * 2 + 1];
#pragma unroll
                    for (int ndt = 0; ndt < 2; ++ndt) {
                        const bf16x8 Vf =
                            *(const bf16x8*)(Vs + (ndt * 32 + l31) * 72 +
                                             t32 * 32 + tau * 16 + hsel * 8);
                        X[qt][ndt] = MFMA32(Af.v, Vf, X[qt][ndt]);  // D[q][d]
                    }
                }
            }
        }
    }

    // ---- epilogue: den reduce, normalize, stage to LDS, coalesced store ----
#pragma unroll
    for (int qt = 0; qt < 2; ++qt) {
        den[qt] += __shfl_xor(den[qt], 32);
        denb[w * 64 + qt * 32 + l31] = 1.0f / (den[qt] + 1e-6f);
    }
    u16* Xout = Qs;   // Q frags live in regs; Qs region reused (barriers below)
#pragma unroll
    for (int qt = 0; qt < 2; ++qt) {
        float invv[16];
#pragma unroll
        for (int e = 0; e < 16; ++e)
            invv[e] = denb[w * 64 + qt * 32 + (e & 3) + 8 * (e >> 2) + 4 * hsel];
#pragma unroll
        for (int ndt = 0; ndt < 2; ++ndt)
#pragma unroll
            for (int e = 0; e < 16; ++e) {
                const int rho = (e & 3) + 8 * (e >> 2) + 4 * hsel;
                Xout[(w * 64 + qt * 32 + rho) * 72 + ndt * 32 + l31] =
                    f2bf(X[qt][ndt][e] * invv[e]);
            }
    }
    __syncthreads();
#pragma unroll
    for (int rg = 0; rg < 4; ++rg) {
        const int r = rg * 64 + sr;
#pragma unroll
        for (int g = 0; g < 2; ++g) {
            const int ch = sc4 + g * 4;
            *(u16x8*)(Xb + (bS + q0 + r) * Ddim + col0 + ch * 8) =
                *(const u16x8*)(Xout + r * 72 + ch * 8);
        }
    }
}

// ---------------------------------------------------------------------------
extern "C" void kernel_launch(void* const* d_in, const int* in_sizes, int n_in,
                              void* d_out, int out_size, void* d_ws, size_t ws_size,
                              hipStream_t stream) {
    const float* query   = (const float*)d_in[0];
    const float* key     = (const float*)d_in[1];
    const float* value   = (const float*)d_in[2];
    const float* policy  = (const float*)d_in[3];
    const float* wq_w    = (const float*)d_in[4];
    const float* wq_b    = (const float*)d_in[5];
    const float* wk_w    = (const float*)d_in[6];
    const float* wk_b    = (const float*)d_in[7];
    const float* wv_w    = (const float*)d_in[8];
    const float* wv_b    = (const float*)d_in[9];
    const float* dense_w = (const float*)d_in[10];
    const float* dense_b = (const float*)d_in[11];

    const size_t MM = 1u << 20;
    const size_t A8 = 8 * MM;
    u16* qa  = (u16*)d_ws;        // later aliased as Xb
    u16* ka  = qa + A8;           // later aliased as Vtg
    u16* va  = ka + A8;
    u16* wqb = va + A8;
    u16* wkb = wqb + MM;
    u16* wvb = wkb + MM;
    u16* wdb = wvb + MM;
    u16* Qp  = wdb + MM;
    u16* Kp  = Qp + A8;
    u16* Vp  = Kp + A8;
    u16* Vtg = ka;                // safe: ka consumed by gemm8_qkv before transp_v
    u16* Xb  = qa;                // safe: qa consumed by gemm8_qkv before attn

    cvt_all<<<dim3(4096, 7), 256, 0, stream>>>(query, key, value, wq_w, wk_w, wv_w, dense_w,
                                               qa, ka, va, wqb, wkb, wvb, wdb);

    gemm8_qkv<<<dim3(4, 32, 3), 512, 0, stream>>>(qa, ka, va, wqb, wkb, wvb,
                                                  wq_b, wk_b, wv_b, Qp, Kp, Vp);
    transp_v<<<dim3(128, 16), 256, 0, stream>>>(Vp, Vtg);

    attn_mfma<<<dim3(4, 128), 256, 0, stream>>>(Qp, Kp, Vtg, policy, Xb);

    gemm8_dense<<<dim3(4, 32), 512, 0, stream>>>(Xb, wdb, dense_b, (float*)d_out);
}

// Round 4
// 298.666 us; speedup vs baseline: 1.0516x; 1.0263x over previous
//
#include <hip/hip_runtime.h>

// MultiHeadedAttention B=8,S=1024,D=1024,H=16,dk=64 — bf16 MFMA pipeline.
// R8: GEMMs on the canonical min-2-phase template (guide T3 recipe):
// per K-tile {STAGE(t+1) -> compute(t) -> __syncthreads()}, double-buffered
// LDS, ONE barrier per tile, staging slack = full tile compute. Geometry
// 256x128 tile / BK=64 / 8 waves (wave=64x64) so QKV = 768 WGs = 3 exact
// residency rounds and dense = 256 WGs = 1 exact round. XOR chunk swizzle
// (verified conflict-free in R7) + bijective XCD swizzle kept; per-phase
// barriers/vmcnt and setprio dropped (R7 post-mortem: oversynchronized,
// 1 block/CU had nothing to hide stalls). Attention unchanged from R4.

#define Sdim 1024
#define Ddim 1024

typedef unsigned short u16;
typedef float f32x4 __attribute__((ext_vector_type(4)));
typedef float f32x16 __attribute__((ext_vector_type(16)));
typedef __bf16 bf16x8 __attribute__((ext_vector_type(8)));
typedef u16 u16x8 __attribute__((ext_vector_type(8)));
typedef __attribute__((address_space(3))) void lds_void;
typedef __attribute__((address_space(1))) void gbl_void;

__device__ __forceinline__ u16 f2bf(float f) {
    unsigned u = __float_as_uint(f);
    u += 0x7fffu + ((u >> 16) & 1u);   // RNE
    return (u16)(u >> 16);
}
__device__ __forceinline__ void gld16(const void* g, void* l) {
    __builtin_amdgcn_global_load_lds((const gbl_void*)g, (lds_void*)l, 16, 0, 0);
}
// pack two f32 -> two bf16 (round-half-up) in one u32 via v_perm
__device__ __forceinline__ unsigned pk_bf16(float lo, float hi) {
    const unsigned ul = __float_as_uint(lo) + 0x8000u;
    const unsigned uh = __float_as_uint(hi) + 0x8000u;
    return __builtin_amdgcn_perm(uh, ul, 0x07060302u);
}
#define MFMA16(a, b, c) __builtin_amdgcn_mfma_f32_16x16x32_bf16((a), (b), (c), 0, 0, 0)
#define MFMA32(a, b, c) __builtin_amdgcn_mfma_f32_32x32x16_bf16((a), (b), (c), 0, 0, 0)
#define SCHEDB() __builtin_amdgcn_sched_barrier(0)

// ---------------------------------------------------------------------------
// fused fp32->bf16 converts; y=0..2 activations (8M), y=3..6 weights (1M).
// y==3 (wq) is scaled by 0.125 (folds the 1/sqrt(dk) into Q projection).
// ---------------------------------------------------------------------------
__global__ __launch_bounds__(256) void cvt_all(const float* __restrict__ s0,
                                               const float* __restrict__ s1,
                                               const float* __restrict__ s2,
                                               const float* __restrict__ s3,
                                               const float* __restrict__ s4,
                                               const float* __restrict__ s5,
                                               const float* __restrict__ s6,
                                               u16* __restrict__ d0, u16* __restrict__ d1,
                                               u16* __restrict__ d2, u16* __restrict__ d3,
                                               u16* __restrict__ d4, u16* __restrict__ d5,
                                               u16* __restrict__ d6) {
    const int z = blockIdx.y;
    if (z >= 3 && blockIdx.x >= 512) return;
    const float* s = z == 0 ? s0 : z == 1 ? s1 : z == 2 ? s2 : z == 3 ? s3
                   : z == 4 ? s4 : z == 5 ? s5 : s6;
    u16* d = z == 0 ? d0 : z == 1 ? d1 : z == 2 ? d2 : z == 3 ? d3
           : z == 4 ? d4 : z == 5 ? d5 : d6;
    const float sc = (z == 3) ? 0.125f : 1.0f;
    const int i = (blockIdx.x * 256 + threadIdx.x) * 8;
    const float4 a = *(const float4*)(s + i);
    const float4 b = *(const float4*)(s + i + 4);
    u16x8 o;
    o[0] = f2bf(a.x * sc); o[1] = f2bf(a.y * sc); o[2] = f2bf(a.z * sc); o[3] = f2bf(a.w * sc);
    o[4] = f2bf(b.x * sc); o[5] = f2bf(b.y * sc); o[6] = f2bf(b.z * sc); o[7] = f2bf(b.w * sc);
    *(u16x8*)(d + i) = o;
}

// ---------------------------------------------------------------------------
// min-2-phase GEMM: C[M][1024] = A[M][1024] @ W[1024][1024]^T + bias*bscale
// Tile 256x128, BK=64, 512 thr = 8 waves (4Mx2N grid, wave owns 64x64).
// LDS 96 KiB: As[2][256 rows][64 u16] @0 (2x32 KiB), Bs[2][128][64] @65536.
// Row r holds global row r; 16B chunk c stores global chunk c^(r&7) — XOR
// swizzle on ds_read addr, inverse on global_load_lds source (rule 21;
// verified conflict-free in R7: SQ_LDS_BANK_CONFLICT = 0).
// Per tile: STAGE(t+1) [6 gld16/wave] -> compute(t) [16 ds_read_b128,
// 32 MFMA] -> __syncthreads() (the vmcnt(0) inside has full-tile slack).
// ---------------------------------------------------------------------------
template <bool OUT_BF16>
__device__ __forceinline__ void gemm2p_body(const u16* __restrict__ A,
                                            const u16* __restrict__ W,
                                            const float* __restrict__ bias, float bscale,
                                            void* __restrict__ Cout,
                                            char* __restrict__ smem,
                                            int m0, int n0) {
    const int tid  = threadIdx.x;
    const int w    = tid >> 6;
    const int lane = tid & 63;
    const int l15  = lane & 15;
    const int quad = lane >> 4;
    const int wr   = w >> 1;          // 0..3 : 64-row block
    const int wc   = w & 1;           // 0..1 : 64-col block

    // staging: per-lane global src (inverse-swizzled cols), linear LDS dest.
    // wave w stages A rows [w*32, w*32+32) and B rows [w*16, w*16+16).
    const int lrow = lane >> 3;                       // 0..7
    const int scol = (((lane & 7) ^ lrow) << 3);      // u16 units
    const u16* pa = A + (size_t)(m0 + w * 32 + lrow) * Ddim + scol;
    const u16* pb = W + (size_t)(n0 + w * 16 + lrow) * Ddim + scol;
    char* sAw = smem + w * 4096;                      // + buf*32768 + j*1024
    char* sBw = smem + 65536 + w * 2048;              // + buf*16384 + j*1024

#define STG(t, b)                                                             \
    do {                                                                      \
        const int k0 = (t) * 64;                                              \
        gld16(pa + k0,             sAw + (b) * 32768);                        \
        gld16(pa + k0 + 8 * 1024,  sAw + (b) * 32768 + 1024);                 \
        gld16(pa + k0 + 16 * 1024, sAw + (b) * 32768 + 2048);                 \
        gld16(pa + k0 + 24 * 1024, sAw + (b) * 32768 + 3072);                 \
        gld16(pb + k0,             sBw + (b) * 16384);                        \
        gld16(pb + k0 + 8 * 1024,  sBw + (b) * 16384 + 1024);                 \
    } while (0)

    // fragment read addressing (swizzled)
    const char* Ab = smem + (size_t)(wr * 64 + l15) * 128;
    const char* Bb = smem + 65536 + (size_t)(wc * 64 + l15) * 128;
    const int cx = ((quad ^ (l15 & 7)) << 4);   // ks=0 col-byte; ks=1 is cx^64

    f32x4 acc[4][4] = {};

    STG(0, 0);
    __syncthreads();

    for (int t = 0; t < 16; ++t) {
        const int boA = (t & 1) * 32768;
        const int boB = (t & 1) * 16384;
        if (t < 15) STG(t + 1, (t & 1) ^ 1);
        SCHEDB();   // pin staging issue before compute
#pragma unroll
        for (int ks = 0; ks < 2; ++ks) {
            const int cxs = cx ^ (ks << 6);
            bf16x8 af[4], bfr[4];
#pragma unroll
            for (int i = 0; i < 4; ++i)
                af[i] = *(const bf16x8*)(Ab + boA + i * 2048 + cxs);
#pragma unroll
            for (int j = 0; j < 4; ++j)
                bfr[j] = *(const bf16x8*)(Bb + boB + j * 2048 + cxs);
#pragma unroll
            for (int i = 0; i < 4; ++i)
#pragma unroll
                for (int j = 0; j < 4; ++j)
                    acc[i][j] = MFMA16(af[i], bfr[j], acc[i][j]);
        }
        __syncthreads();   // vmcnt(0)+lgkmcnt(0)+barrier: publishes buf for t+1
    }
#undef STG

    // ---- epilogue ----
    float bv[4];
#pragma unroll
    for (int j = 0; j < 4; ++j)
        bv[j] = bias[n0 + wc * 64 + j * 16 + l15] * bscale;
#pragma unroll
    for (int i = 0; i < 4; ++i)
#pragma unroll
        for (int j = 0; j < 4; ++j)
#pragma unroll
            for (int r = 0; r < 4; ++r) {
                const int row = m0 + wr * 64 + i * 16 + quad * 4 + r;
                const int col = n0 + wc * 64 + j * 16 + l15;
                const float v = acc[i][j][r] + bv[j];
                if (OUT_BF16)
                    ((u16*)Cout)[(size_t)row * Ddim + col] = f2bf(v);
                else
                    ((float*)Cout)[(size_t)row * Ddim + col] = v;
            }
}

__global__ __launch_bounds__(512, 2) void gemm2p_qkv(
        const u16* __restrict__ A0, const u16* __restrict__ A1, const u16* __restrict__ A2,
        const u16* __restrict__ W0, const u16* __restrict__ W1, const u16* __restrict__ W2,
        const float* __restrict__ b0, const float* __restrict__ b1, const float* __restrict__ b2,
        u16* __restrict__ C0, u16* __restrict__ C1, u16* __restrict__ C2) {
    __shared__ __align__(16) char smem[98304];
    // bijective XCD swizzle over 768 WGs (768 % 8 == 0)
    const int d = blockIdx.x;
    const int s = (d & 7) * 96 + (d >> 3);
    const int z = s >> 8;                 // 256 tiles per z
    const int rr = s & 255;
    const int tm = rr >> 3, tn = rr & 7;  // 32 x 8 tiles
    const u16* A = z == 0 ? A0 : z == 1 ? A1 : A2;
    const u16* W = z == 0 ? W0 : z == 1 ? W1 : W2;
    const float* bias = z == 0 ? b0 : z == 1 ? b1 : b2;
    u16* C = z == 0 ? C0 : z == 1 ? C1 : C2;
    const float bsc = (z == 0) ? 0.125f : 1.0f;   // wq path is pre-scaled
    gemm2p_body<true>(A, W, bias, bsc, (void*)C, smem, tm * 256, tn * 128);
}

__global__ __launch_bounds__(512, 2) void gemm2p_dense(const u16* __restrict__ A,
                                                       const u16* __restrict__ W,
                                                       const float* __restrict__ bias,
                                                       float* __restrict__ C) {
    __shared__ __align__(16) char smem[98304];
    const int d = blockIdx.x;             // 256 WGs
    const int s = (d & 7) * 32 + (d >> 3);
    const int tm = s >> 3, tn = s & 7;
    gemm2p_body<false>(A, W, bias, 1.0f, (void*)C, smem, tm * 256, tn * 128);
}

// ---------------------------------------------------------------------------
// V transpose: Vp[B*S][D] (bf16) -> Vt_g[(b*16+h)*64 + d][S]
// ---------------------------------------------------------------------------
__global__ __launch_bounds__(256) void transp_v(const u16* __restrict__ Vp,
                                                u16* __restrict__ Vt) {
    __shared__ __align__(16) u16 Ts[64][72];
    const int bh = blockIdx.x, s0 = blockIdx.y * 64;
    const int b = bh >> 4, h = bh & 15;
    const int tid = threadIdx.x;
#pragma unroll
    for (int p = 0; p < 2; ++p) {
        const int e = p * 2048 + tid * 8;
        const int r = e >> 6, c = e & 63;
        *(u16x8*)&Ts[r][c] =
            *(const u16x8*)(Vp + ((size_t)(b * Sdim + s0 + r)) * Ddim + h * 64 + c);
    }
    __syncthreads();
    const int d = tid >> 2, sp = tid & 3;
#pragma unroll
    for (int g = 0; g < 2; ++g) {
        u16x8 o;
#pragma unroll
        for (int j = 0; j < 8; ++j) o[j] = Ts[sp * 16 + g * 8 + j][d];
        *(u16x8*)(Vt + ((size_t)(bh * 64 + d)) * Sdim + s0 + sp * 16 + g * 8) = o;
    }
}

// ---------------------------------------------------------------------------
// Attention on 32x32 MFMA. Block = 256 q-rows of one (b,h); wave owns 64 q.
// Per 64-kpos tile: S^T = K.Q^T (A=K-frag, B=Q-frag cached in regs);
// p = exp(s)*pol in f32; P regs re-laid C->A via shfl_xor(32)+cndmask;
// X += P.V^T. All LDS tiles stride 72 u16 (conflict-free for 32-row frags).
// ---------------------------------------------------------------------------
__global__ __launch_bounds__(256, 2) void attn_mfma(const u16* __restrict__ Qp,
                                                    const u16* __restrict__ Kp,
                                                    const u16* __restrict__ Vt,
                                                    const float* __restrict__ pol,
                                                    u16* __restrict__ Xb) {
    __shared__ __align__(16) u16 lds[28288];    // 56576 B
    u16* Qs = lds;                              // 256 x 72  (later: Xout)
    u16* Ks = lds + 18432;                      // 64 x 72   K[kpos][dk]
    u16* Vs = lds + 23040;                      // 64 x 72   V^T[d][kpos]
    float* pols = (float*)(lds + 27648);        // [64]
    float* denb = pols + 64;                    // [256] inv-den

    const int tid  = threadIdx.x;
    const int w    = tid >> 6;
    const int lane = tid & 63;
    const int l31  = lane & 31;
    const unsigned hsel = lane >> 5;            // half selector
    const int q0 = blockIdx.x * 256;
    const int bh = blockIdx.y;
    const size_t bS = (size_t)(bh >> 4) * Sdim;
    const int col0 = (bh & 15) * 64;
    const int sr = tid >> 2;                    // staging row 0..63
    const int sc4 = tid & 3;                    // staging chunk base

    // ---- stage Q tile 256x64 and load Q B-frags into registers ----
#pragma unroll
    for (int rg = 0; rg < 4; ++rg) {
        const int r = rg * 64 + sr;
#pragma unroll
        for (int g = 0; g < 2; ++g) {
            const int ch = sc4 + g * 4;
            *(u16x8*)(Qs + r * 72 + ch * 8) =
                *(const u16x8*)(Qp + (bS + q0 + r) * Ddim + col0 + ch * 8);
        }
    }
    __syncthreads();
    bf16x8 Qf[2][4];
#pragma unroll
    for (int qt = 0; qt < 2; ++qt)
#pragma unroll
        for (int dkt = 0; dkt < 4; ++dkt)
            Qf[qt][dkt] = *(const bf16x8*)(Qs + (w * 64 + qt * 32 + l31) * 72 +
                                           dkt * 16 + hsel * 8);

    f32x16 X[2][2] = {};
    float den[2] = {0.f, 0.f};

    for (int kt = 0; kt < 16; ++kt) {
        const int kbase = kt * 64;
        __syncthreads();
        // stage K[64][64] and V^T[64][64]
#pragma unroll
        for (int g = 0; g < 2; ++g) {
            const int ch = sc4 + g * 4;
            *(u16x8*)(Ks + sr * 72 + ch * 8) =
                *(const u16x8*)(Kp + (bS + kbase + sr) * Ddim + col0 + ch * 8);
            *(u16x8*)(Vs + sr * 72 + ch * 8) =
                *(const u16x8*)(Vt + ((size_t)(bh * 64 + sr)) * Sdim + kbase + ch * 8);
        }
        if (tid < 64) pols[tid] = pol[bS + kbase + tid];
        __syncthreads();

#pragma unroll
        for (int t32 = 0; t32 < 2; ++t32) {
            // pol per C-layout row (broadcast reads; uniform per (e,half))
            float polv[16];
#pragma unroll
            for (int e = 0; e < 16; ++e)
                polv[e] = pols[t32 * 32 + (e & 3) + 8 * (e >> 2) + 4 * hsel];
            bf16x8 Kf[4];
#pragma unroll
            for (int dkt = 0; dkt < 4; ++dkt)
                Kf[dkt] = *(const bf16x8*)(Ks + (t32 * 32 + l31) * 72 +
                                           dkt * 16 + hsel * 8);
#pragma unroll
            for (int qt = 0; qt < 2; ++qt) {
                f32x16 S = {};
#pragma unroll
                for (int dkt = 0; dkt < 4; ++dkt)
                    S = MFMA32(Kf[dkt], Qf[qt][dkt], S);   // D[kpos][q]
                // softmax numerator (f32), accumulate den per-lane (q = l31)
                float p[16];
#pragma unroll
                for (int e = 0; e < 16; ++e) {
                    p[e] = __expf(S[e]) * polv[e];
                    den[qt] += p[e];
                }
                // pack pairs along kpos rows: pk_[2g]=(c0,c1), pk_[2g+1]=(c2,c3)
                unsigned pk_[8], sw[8];
#pragma unroll
                for (int g = 0; g < 4; ++g) {
                    pk_[2 * g]     = pk_bf16(p[4 * g + 0], p[4 * g + 1]);
                    pk_[2 * g + 1] = pk_bf16(p[4 * g + 2], p[4 * g + 3]);
                }
#pragma unroll
                for (int i = 0; i < 8; ++i)
                    sw[i] = (unsigned)__shfl_xor((int)pk_[i], 32);
                // P A-frags for the two 16-k tiles of this 32-kpos block
#pragma unroll
                for (int tau = 0; tau < 2; ++tau) {
                    union { unsigned u[4]; bf16x8 v; } Af;
                    Af.u[0] = hsel ? sw[(2 * tau + 1) * 2 + 0] : pk_[(2 * tau) * 2 + 0];
                    Af.u[1] = hsel ? sw[(2 * tau + 1) * 2 + 1] : pk_[(2 * tau) * 2 + 1];
                    Af.u[2] = hsel ? pk_[(2 * tau + 1) * 2 + 0] : sw[(2 * tau) * 2 + 0];
                    Af.u[3] = hsel ? pk_[(2 * tau + 1) * 2 + 1] : sw[(2 * tau) * 2 + 1];
#pragma unroll
                    for (int ndt = 0; ndt < 2; ++ndt) {
                        const bf16x8 Vf =
                            *(const bf16x8*)(Vs + (ndt * 32 + l31) * 72 +
                                             t32 * 32 + tau * 16 + hsel * 8);
                        X[qt][ndt] = MFMA32(Af.v, Vf, X[qt][ndt]);  // D[q][d]
                    }
                }
            }
        }
    }

    // ---- epilogue: den reduce, normalize, stage to LDS, coalesced store ----
#pragma unroll
    for (int qt = 0; qt < 2; ++qt) {
        den[qt] += __shfl_xor(den[qt], 32);
        denb[w * 64 + qt * 32 + l31] = 1.0f / (den[qt] + 1e-6f);
    }
    u16* Xout = Qs;   // Q frags live in regs; Qs region reused (barriers below)
#pragma unroll
    for (int qt = 0; qt < 2; ++qt) {
        float invv[16];
#pragma unroll
        for (int e = 0; e < 16; ++e)
            invv[e] = denb[w * 64 + qt * 32 + (e & 3) + 8 * (e >> 2) + 4 * hsel];
#pragma unroll
        for (int ndt = 0; ndt < 2; ++ndt)
#pragma unroll
            for (int e = 0; e < 16; ++e) {
                const int rho = (e & 3) + 8 * (e >> 2) + 4 * hsel;
                Xout[(w * 64 + qt * 32 + rho) * 72 + ndt * 32 + l31] =
                    f2bf(X[qt][ndt][e] * invv[e]);
            }
    }
    __syncthreads();
#pragma unroll
    for (int rg = 0; rg < 4; ++rg) {
        const int r = rg * 64 + sr;
#pragma unroll
        for (int g = 0; g < 2; ++g) {
            const int ch = sc4 + g * 4;
            *(u16x8*)(Xb + (bS + q0 + r) * Ddim + col0 + ch * 8) =
                *(const u16x8*)(Xout + r * 72 + ch * 8);
        }
    }
}

// ---------------------------------------------------------------------------
extern "C" void kernel_launch(void* const* d_in, const int* in_sizes, int n_in,
                              void* d_out, int out_size, void* d_ws, size_t ws_size,
                              hipStream_t stream) {
    const float* query   = (const float*)d_in[0];
    const float* key     = (const float*)d_in[1];
    const float* value   = (const float*)d_in[2];
    const float* policy  = (const float*)d_in[3];
    const float* wq_w    = (const float*)d_in[4];
    const float* wq_b    = (const float*)d_in[5];
    const float* wk_w    = (const float*)d_in[6];
    const float* wk_b    = (const float*)d_in[7];
    const float* wv_w    = (const float*)d_in[8];
    const float* wv_b    = (const float*)d_in[9];
    const float* dense_w = (const float*)d_in[10];
    const float* dense_b = (const float*)d_in[11];

    const size_t MM = 1u << 20;
    const size_t A8 = 8 * MM;
    u16* qa  = (u16*)d_ws;        // later aliased as Xb
    u16* ka  = qa + A8;           // later aliased as Vtg
    u16* va  = ka + A8;
    u16* wqb = va + A8;
    u16* wkb = wqb + MM;
    u16* wvb = wkb + MM;
    u16* wdb = wvb + MM;
    u16* Qp  = wdb + MM;
    u16* Kp  = Qp + A8;
    u16* Vp  = Kp + A8;
    u16* Vtg = ka;                // safe: ka consumed by gemm2p_qkv before transp_v
    u16* Xb  = qa;                // safe: qa consumed by gemm2p_qkv before attn

    cvt_all<<<dim3(4096, 7), 256, 0, stream>>>(query, key, value, wq_w, wk_w, wv_w, dense_w,
                                               qa, ka, va, wqb, wkb, wvb, wdb);

    gemm2p_qkv<<<dim3(768), 512, 0, stream>>>(qa, ka, va, wqb, wkb, wvb,
                                              wq_b, wk_b, wv_b, Qp, Kp, Vp);
    transp_v<<<dim3(128, 16), 256, 0, stream>>>(Vp, Vtg);

    attn_mfma<<<dim3(4, 128), 256, 0, stream>>>(Qp, Kp, Vtg, policy, Xb);

    gemm2p_dense<<<dim3(256), 512, 0, stream>>>(Xb, wdb, dense_b, (float*)d_out);
}

// Round 5
// 294.951 us; speedup vs baseline: 1.0648x; 1.0126x over previous
//
#include <hip/hip_runtime.h>

// MultiHeadedAttention B=8,S=1024,D=1024,H=16,dk=64 — bf16 MFMA pipeline.
// R9: attention VALU-diet + async staging (R8 post-mortem: VALUBusy 42% vs
// MfmaUtil 21%, serial staging between 2 barriers/kt):
//  - exp2-fold: wq cvt scale = 0.125*log2(e); p = exp2(S)*pol via native v_exp
//  - v_cvt_pk_bf16_f32 (1 inst) replaces add/add/perm pack (3 inst)
//  - permlane32_swap replaces shfl_xor(32)+cndmask C->A relayout
//  - T14: double-buffered K/V/pol LDS, loads issued before compute, LDS
//    writes after, ONE barrier per kt (was 2)
//  - grid (128,4): 4 q-blocks of one (b,h) share an XCD -> K/V L2 reuse
// GEMMs (R8 2-phase template) and transp_v unchanged.

#define Sdim 1024
#define Ddim 1024

typedef unsigned short u16;
typedef float f32x4 __attribute__((ext_vector_type(4)));
typedef float f32x16 __attribute__((ext_vector_type(16)));
typedef __bf16 bf16x8 __attribute__((ext_vector_type(8)));
typedef u16 u16x8 __attribute__((ext_vector_type(8)));
typedef unsigned u32x2 __attribute__((ext_vector_type(2)));
typedef __attribute__((address_space(3))) void lds_void;
typedef __attribute__((address_space(1))) void gbl_void;

__device__ __forceinline__ u16 f2bf(float f) {
    unsigned u = __float_as_uint(f);
    u += 0x7fffu + ((u >> 16) & 1u);   // RNE
    return (u16)(u >> 16);
}
__device__ __forceinline__ void gld16(const void* g, void* l) {
    __builtin_amdgcn_global_load_lds((const gbl_void*)g, (lds_void*)l, 16, 0, 0);
}
__device__ __forceinline__ float fexp2(float x) {
#if __has_builtin(__builtin_amdgcn_exp2f)
    return __builtin_amdgcn_exp2f(x);
#else
    return __expf(x * 0.6931471805599453f);
#endif
}
// pack two f32 -> 2x bf16 (RNE) in one u32: v_cvt_pk_bf16_f32 (no builtin)
__device__ __forceinline__ unsigned cvtpk(float lo, float hi) {
    unsigned r;
    asm("v_cvt_pk_bf16_f32 %0, %1, %2" : "=v"(r) : "v"(lo), "v"(hi));
    return r;
}
#define MFMA16(a, b, c) __builtin_amdgcn_mfma_f32_16x16x32_bf16((a), (b), (c), 0, 0, 0)
#define MFMA32(a, b, c) __builtin_amdgcn_mfma_f32_32x32x16_bf16((a), (b), (c), 0, 0, 0)
#define SCHEDB() __builtin_amdgcn_sched_barrier(0)

#define QSCALE 0.18033688011112042f   // 0.125 * log2(e)

// ---------------------------------------------------------------------------
// fused fp32->bf16 converts; y=0..2 activations (8M), y=3..6 weights (1M).
// y==3 (wq) is scaled by 0.125*log2e (folds 1/sqrt(dk) AND exp->exp2).
// ---------------------------------------------------------------------------
__global__ __launch_bounds__(256) void cvt_all(const float* __restrict__ s0,
                                               const float* __restrict__ s1,
                                               const float* __restrict__ s2,
                                               const float* __restrict__ s3,
                                               const float* __restrict__ s4,
                                               const float* __restrict__ s5,
                                               const float* __restrict__ s6,
                                               u16* __restrict__ d0, u16* __restrict__ d1,
                                               u16* __restrict__ d2, u16* __restrict__ d3,
                                               u16* __restrict__ d4, u16* __restrict__ d5,
                                               u16* __restrict__ d6) {
    const int z = blockIdx.y;
    if (z >= 3 && blockIdx.x >= 512) return;
    const float* s = z == 0 ? s0 : z == 1 ? s1 : z == 2 ? s2 : z == 3 ? s3
                   : z == 4 ? s4 : z == 5 ? s5 : s6;
    u16* d = z == 0 ? d0 : z == 1 ? d1 : z == 2 ? d2 : z == 3 ? d3
           : z == 4 ? d4 : z == 5 ? d5 : d6;
    const float sc = (z == 3) ? QSCALE : 1.0f;
    const int i = (blockIdx.x * 256 + threadIdx.x) * 8;
    const float4 a = *(const float4*)(s + i);
    const float4 b = *(const float4*)(s + i + 4);
    u16x8 o;
    o[0] = f2bf(a.x * sc); o[1] = f2bf(a.y * sc); o[2] = f2bf(a.z * sc); o[3] = f2bf(a.w * sc);
    o[4] = f2bf(b.x * sc); o[5] = f2bf(b.y * sc); o[6] = f2bf(b.z * sc); o[7] = f2bf(b.w * sc);
    *(u16x8*)(d + i) = o;
}

// ---------------------------------------------------------------------------
// min-2-phase GEMM (unchanged from R8): tile 256x128, BK=64, 8 waves.
// ---------------------------------------------------------------------------
template <bool OUT_BF16>
__device__ __forceinline__ void gemm2p_body(const u16* __restrict__ A,
                                            const u16* __restrict__ W,
                                            const float* __restrict__ bias, float bscale,
                                            void* __restrict__ Cout,
                                            char* __restrict__ smem,
                                            int m0, int n0) {
    const int tid  = threadIdx.x;
    const int w    = tid >> 6;
    const int lane = tid & 63;
    const int l15  = lane & 15;
    const int quad = lane >> 4;
    const int wr   = w >> 1;          // 0..3 : 64-row block
    const int wc   = w & 1;           // 0..1 : 64-col block

    const int lrow = lane >> 3;                       // 0..7
    const int scol = (((lane & 7) ^ lrow) << 3);      // u16 units
    const u16* pa = A + (size_t)(m0 + w * 32 + lrow) * Ddim + scol;
    const u16* pb = W + (size_t)(n0 + w * 16 + lrow) * Ddim + scol;
    char* sAw = smem + w * 4096;
    char* sBw = smem + 65536 + w * 2048;

#define STG(t, b)                                                             \
    do {                                                                      \
        const int k0 = (t) * 64;                                              \
        gld16(pa + k0,             sAw + (b) * 32768);                        \
        gld16(pa + k0 + 8 * 1024,  sAw + (b) * 32768 + 1024);                 \
        gld16(pa + k0 + 16 * 1024, sAw + (b) * 32768 + 2048);                 \
        gld16(pa + k0 + 24 * 1024, sAw + (b) * 32768 + 3072);                 \
        gld16(pb + k0,             sBw + (b) * 16384);                        \
        gld16(pb + k0 + 8 * 1024,  sBw + (b) * 16384 + 1024);                 \
    } while (0)

    const char* Ab = smem + (size_t)(wr * 64 + l15) * 128;
    const char* Bb = smem + 65536 + (size_t)(wc * 64 + l15) * 128;
    const int cx = ((quad ^ (l15 & 7)) << 4);

    f32x4 acc[4][4] = {};

    STG(0, 0);
    __syncthreads();

    for (int t = 0; t < 16; ++t) {
        const int boA = (t & 1) * 32768;
        const int boB = (t & 1) * 16384;
        if (t < 15) STG(t + 1, (t & 1) ^ 1);
        SCHEDB();
#pragma unroll
        for (int ks = 0; ks < 2; ++ks) {
            const int cxs = cx ^ (ks << 6);
            bf16x8 af[4], bfr[4];
#pragma unroll
            for (int i = 0; i < 4; ++i)
                af[i] = *(const bf16x8*)(Ab + boA + i * 2048 + cxs);
#pragma unroll
            for (int j = 0; j < 4; ++j)
                bfr[j] = *(const bf16x8*)(Bb + boB + j * 2048 + cxs);
#pragma unroll
            for (int i = 0; i < 4; ++i)
#pragma unroll
                for (int j = 0; j < 4; ++j)
                    acc[i][j] = MFMA16(af[i], bfr[j], acc[i][j]);
        }
        __syncthreads();
    }
#undef STG

    float bv[4];
#pragma unroll
    for (int j = 0; j < 4; ++j)
        bv[j] = bias[n0 + wc * 64 + j * 16 + l15] * bscale;
#pragma unroll
    for (int i = 0; i < 4; ++i)
#pragma unroll
        for (int j = 0; j < 4; ++j)
#pragma unroll
            for (int r = 0; r < 4; ++r) {
                const int row = m0 + wr * 64 + i * 16 + quad * 4 + r;
                const int col = n0 + wc * 64 + j * 16 + l15;
                const float v = acc[i][j][r] + bv[j];
                if (OUT_BF16)
                    ((u16*)Cout)[(size_t)row * Ddim + col] = f2bf(v);
                else
                    ((float*)Cout)[(size_t)row * Ddim + col] = v;
            }
}

__global__ __launch_bounds__(512, 2) void gemm2p_qkv(
        const u16* __restrict__ A0, const u16* __restrict__ A1, const u16* __restrict__ A2,
        const u16* __restrict__ W0, const u16* __restrict__ W1, const u16* __restrict__ W2,
        const float* __restrict__ b0, const float* __restrict__ b1, const float* __restrict__ b2,
        u16* __restrict__ C0, u16* __restrict__ C1, u16* __restrict__ C2) {
    __shared__ __align__(16) char smem[98304];
    const int d = blockIdx.x;
    const int s = (d & 7) * 96 + (d >> 3);
    const int z = s >> 8;
    const int rr = s & 255;
    const int tm = rr >> 3, tn = rr & 7;
    const u16* A = z == 0 ? A0 : z == 1 ? A1 : A2;
    const u16* W = z == 0 ? W0 : z == 1 ? W1 : W2;
    const float* bias = z == 0 ? b0 : z == 1 ? b1 : b2;
    u16* C = z == 0 ? C0 : z == 1 ? C1 : C2;
    const float bsc = (z == 0) ? QSCALE : 1.0f;   // wq path is pre-scaled
    gemm2p_body<true>(A, W, bias, bsc, (void*)C, smem, tm * 256, tn * 128);
}

__global__ __launch_bounds__(512, 2) void gemm2p_dense(const u16* __restrict__ A,
                                                       const u16* __restrict__ W,
                                                       const float* __restrict__ bias,
                                                       float* __restrict__ C) {
    __shared__ __align__(16) char smem[98304];
    const int d = blockIdx.x;
    const int s = (d & 7) * 32 + (d >> 3);
    const int tm = s >> 3, tn = s & 7;
    gemm2p_body<false>(A, W, bias, 1.0f, (void*)C, smem, tm * 256, tn * 128);
}

// ---------------------------------------------------------------------------
// V transpose: Vp[B*S][D] (bf16) -> Vt_g[(b*16+h)*64 + d][S]
// ---------------------------------------------------------------------------
__global__ __launch_bounds__(256) void transp_v(const u16* __restrict__ Vp,
                                                u16* __restrict__ Vt) {
    __shared__ __align__(16) u16 Ts[64][72];
    const int bh = blockIdx.x, s0 = blockIdx.y * 64;
    const int b = bh >> 4, h = bh & 15;
    const int tid = threadIdx.x;
#pragma unroll
    for (int p = 0; p < 2; ++p) {
        const int e = p * 2048 + tid * 8;
        const int r = e >> 6, c = e & 63;
        *(u16x8*)&Ts[r][c] =
            *(const u16x8*)(Vp + ((size_t)(b * Sdim + s0 + r)) * Ddim + h * 64 + c);
    }
    __syncthreads();
    const int d = tid >> 2, sp = tid & 3;
#pragma unroll
    for (int g = 0; g < 2; ++g) {
        u16x8 o;
#pragma unroll
        for (int j = 0; j < 8; ++j) o[j] = Ts[sp * 16 + g * 8 + j][d];
        *(u16x8*)(Vt + ((size_t)(bh * 64 + d)) * Sdim + s0 + sp * 16 + g * 8) = o;
    }
}

// ---------------------------------------------------------------------------
// Attention on 32x32 MFMA. Grid (128 bh, 4 qblk) — q-siblings of one (b,h)
// share an XCD (wgid = bh + 128*y, 128%8==0). Block = 256 q-rows; wave = 64 q.
// Per 64-kpos tile: S^T = K.Q^T; p = exp2(S)*pol (wq pre-scaled by
// 0.125*log2e); P C->A relayout via v_cvt_pk_bf16_f32 + permlane32_swap;
// X += P.V^T. K/V/pol double-buffered in LDS; T14: next-tile global loads
// issued before compute, LDS writes after — ONE barrier per kt.
// ---------------------------------------------------------------------------
__global__ __launch_bounds__(256, 2) void attn_mfma(const u16* __restrict__ Qp,
                                                    const u16* __restrict__ Kp,
                                                    const u16* __restrict__ Vt,
                                                    const float* __restrict__ pol,
                                                    u16* __restrict__ Xb) {
    __shared__ __align__(16) u16 lds[37632];    // 75264 B
    u16* Qs = lds;                              // 256 x 72  (later: Xout)
    u16* Ks = lds + 18432;                      // 2 x 64 x 72   K[kpos][dk]
    u16* Vs = lds + 27648;                      // 2 x 64 x 72   V^T[d][kpos]
    float* pols = (float*)(lds + 36864);        // 2 x [64]
    float* denb = pols + 128;                   // [256] inv-den

    const int tid  = threadIdx.x;
    const int w    = tid >> 6;
    const int lane = tid & 63;
    const int l31  = lane & 31;
    const unsigned hsel = lane >> 5;            // half selector
    const int bh = blockIdx.x;
    const int q0 = blockIdx.y * 256;
    const size_t bS = (size_t)(bh >> 4) * Sdim;
    const int col0 = (bh & 15) * 64;
    const int sr = tid >> 2;                    // staging row 0..63
    const int sc4 = tid & 3;                    // staging chunk base

    // staging base pointers (chunk ch = sc4 + g*4)
    const u16* Kg = Kp + (bS + sr) * Ddim + col0 + sc4 * 8;
    const u16* Vg = Vt + ((size_t)(bh * 64 + sr)) * Sdim + sc4 * 8;
    const float* pg = pol + bS + tid;

    // ---- stage Q tile 256x64, K/V/pol tile kt=0 into buf0 ----
#pragma unroll
    for (int rg = 0; rg < 4; ++rg) {
        const int r = rg * 64 + sr;
#pragma unroll
        for (int g = 0; g < 2; ++g) {
            const int ch = sc4 + g * 4;
            *(u16x8*)(Qs + r * 72 + ch * 8) =
                *(const u16x8*)(Qp + (bS + q0 + r) * Ddim + col0 + ch * 8);
        }
    }
#pragma unroll
    for (int g = 0; g < 2; ++g) {
        *(u16x8*)(Ks + sr * 72 + (sc4 + g * 4) * 8) = *(const u16x8*)(Kg + g * 32);
        *(u16x8*)(Vs + sr * 72 + (sc4 + g * 4) * 8) = *(const u16x8*)(Vg + g * 32);
    }
    if (tid < 64) pols[tid] = pg[0];
    __syncthreads();

    bf16x8 Qf[2][4];
#pragma unroll
    for (int qt = 0; qt < 2; ++qt)
#pragma unroll
        for (int dkt = 0; dkt < 4; ++dkt)
            Qf[qt][dkt] = *(const bf16x8*)(Qs + (w * 64 + qt * 32 + l31) * 72 +
                                           dkt * 16 + hsel * 8);

    f32x16 X[2][2] = {};
    float den[2] = {0.f, 0.f};

    for (int kt = 0; kt < 16; ++kt) {
        const int cur = kt & 1;
        const bool pf = (kt < 15);
        // ---- T14 issue-early: next tile's global loads into regs ----
        u16x8 kr0 = {}, kr1 = {}, vr0 = {}, vr1 = {};
        float polr = 0.f;
        if (pf) {
            const int ko = (kt + 1) * 64;
            kr0 = *(const u16x8*)(Kg + (size_t)ko * Ddim);
            kr1 = *(const u16x8*)(Kg + (size_t)ko * Ddim + 32);
            vr0 = *(const u16x8*)(Vg + ko);
            vr1 = *(const u16x8*)(Vg + ko + 32);
            if (tid < 64) polr = pg[ko];
        }
        SCHEDB();   // keep load issue above compute

        const u16* Ksc = Ks + cur * 4608;
        const u16* Vsc = Vs + cur * 4608;
        const float* polc = pols + cur * 64;
#pragma unroll
        for (int t32 = 0; t32 < 2; ++t32) {
            float polv[16];
#pragma unroll
            for (int e = 0; e < 16; ++e)
                polv[e] = polc[t32 * 32 + (e & 3) + 8 * (e >> 2) + 4 * hsel];
            bf16x8 Kf[4];
#pragma unroll
            for (int dkt = 0; dkt < 4; ++dkt)
                Kf[dkt] = *(const bf16x8*)(Ksc + (t32 * 32 + l31) * 72 +
                                           dkt * 16 + hsel * 8);
#pragma unroll
            for (int qt = 0; qt < 2; ++qt) {
                f32x16 S = {};
#pragma unroll
                for (int dkt = 0; dkt < 4; ++dkt)
                    S = MFMA32(Kf[dkt], Qf[qt][dkt], S);   // D[kpos][q]
                float p[16];
#pragma unroll
                for (int e = 0; e < 16; ++e) {
                    p[e] = fexp2(S[e]) * polv[e];
                    den[qt] += p[e];
                }
                // pack pairs along kpos rows (RNE), then C->A via permlane
                unsigned pk_[8];
#pragma unroll
                for (int g = 0; g < 4; ++g) {
                    pk_[2 * g]     = cvtpk(p[4 * g + 0], p[4 * g + 1]);
                    pk_[2 * g + 1] = cvtpk(p[4 * g + 2], p[4 * g + 3]);
                }
#pragma unroll
                for (int tau = 0; tau < 2; ++tau) {
                    const u32x2 sA = __builtin_amdgcn_permlane32_swap(
                        pk_[4 * tau + 0], pk_[4 * tau + 2], false, false);
                    const u32x2 sB = __builtin_amdgcn_permlane32_swap(
                        pk_[4 * tau + 1], pk_[4 * tau + 3], false, false);
                    union { unsigned u[4]; bf16x8 v; } Af;
                    Af.u[0] = sA[0]; Af.u[1] = sB[0];
                    Af.u[2] = sA[1]; Af.u[3] = sB[1];
#pragma unroll
                    for (int ndt = 0; ndt < 2; ++ndt) {
                        const bf16x8 Vf =
                            *(const bf16x8*)(Vsc + (ndt * 32 + l31) * 72 +
                                             t32 * 32 + tau * 16 + hsel * 8);
                        X[qt][ndt] = MFMA32(Af.v, Vf, X[qt][ndt]);  // D[q][d]
                    }
                }
            }
        }
        // ---- T14 write-late: publish next tile into the other buffer ----
        if (pf) {
            const int nxt = cur ^ 1;
            *(u16x8*)(Ks + nxt * 4608 + sr * 72 + sc4 * 8) = kr0;
            *(u16x8*)(Ks + nxt * 4608 + sr * 72 + (sc4 + 4) * 8) = kr1;
            *(u16x8*)(Vs + nxt * 4608 + sr * 72 + sc4 * 8) = vr0;
            *(u16x8*)(Vs + nxt * 4608 + sr * 72 + (sc4 + 4) * 8) = vr1;
            if (tid < 64) pols[nxt * 64 + tid] = polr;
        }
        __syncthreads();
    }

    // ---- epilogue: den reduce, normalize, stage to LDS, coalesced store ----
#pragma unroll
    for (int qt = 0; qt < 2; ++qt) {
        den[qt] += __shfl_xor(den[qt], 32);
        denb[w * 64 + qt * 32 + l31] = 1.0f / (den[qt] + 1e-6f);
    }
    u16* Xout = Qs;   // Q frags live in regs; Qs region reused (barriers below)
#pragma unroll
    for (int qt = 0; qt < 2; ++qt) {
        float invv[16];
#pragma unroll
        for (int e = 0; e < 16; ++e)
            invv[e] = denb[w * 64 + qt * 32 + (e & 3) + 8 * (e >> 2) + 4 * hsel];
#pragma unroll
        for (int ndt = 0; ndt < 2; ++ndt)
#pragma unroll
            for (int e = 0; e < 16; ++e) {
                const int rho = (e & 3) + 8 * (e >> 2) + 4 * hsel;
                Xout[(w * 64 + qt * 32 + rho) * 72 + ndt * 32 + l31] =
                    f2bf(X[qt][ndt][e] * invv[e]);
            }
    }
    __syncthreads();
#pragma unroll
    for (int rg = 0; rg < 4; ++rg) {
        const int r = rg * 64 + sr;
#pragma unroll
        for (int g = 0; g < 2; ++g) {
            const int ch = sc4 + g * 4;
            *(u16x8*)(Xb + (bS + q0 + r) * Ddim + col0 + ch * 8) =
                *(const u16x8*)(Xout + r * 72 + ch * 8);
        }
    }
}

// ---------------------------------------------------------------------------
extern "C" void kernel_launch(void* const* d_in, const int* in_sizes, int n_in,
                              void* d_out, int out_size, void* d_ws, size_t ws_size,
                              hipStream_t stream) {
    const float* query   = (const float*)d_in[0];
    const float* key     = (const float*)d_in[1];
    const float* value   = (const float*)d_in[2];
    const float* policy  = (const float*)d_in[3];
    const float* wq_w    = (const float*)d_in[4];
    const float* wq_b    = (const float*)d_in[5];
    const float* wk_w    = (const float*)d_in[6];
    const float* wk_b    = (const float*)d_in[7];
    const float* wv_w    = (const float*)d_in[8];
    const float* wv_b    = (const float*)d_in[9];
    const float* dense_w = (const float*)d_in[10];
    const float* dense_b = (const float*)d_in[11];

    const size_t MM = 1u << 20;
    const size_t A8 = 8 * MM;
    u16* qa  = (u16*)d_ws;        // later aliased as Xb
    u16* ka  = qa + A8;           // later aliased as Vtg
    u16* va  = ka + A8;
    u16* wqb = va + A8;
    u16* wkb = wqb + MM;
    u16* wvb = wkb + MM;
    u16* wdb = wvb + MM;
    u16* Qp  = wdb + MM;
    u16* Kp  = Qp + A8;
    u16* Vp  = Kp + A8;
    u16* Vtg = ka;                // safe: ka consumed by gemm2p_qkv before transp_v
    u16* Xb  = qa;                // safe: qa consumed by gemm2p_qkv before attn

    cvt_all<<<dim3(4096, 7), 256, 0, stream>>>(query, key, value, wq_w, wk_w, wv_w, dense_w,
                                               qa, ka, va, wqb, wkb, wvb, wdb);

    gemm2p_qkv<<<dim3(768), 512, 0, stream>>>(qa, ka, va, wqb, wkb, wvb,
                                              wq_b, wk_b, wv_b, Qp, Kp, Vp);
    transp_v<<<dim3(128, 16), 256, 0, stream>>>(Vp, Vtg);

    attn_mfma<<<dim3(128, 4), 256, 0, stream>>>(Qp, Kp, Vtg, policy, Xb);

    gemm2p_dense<<<dim3(256), 512, 0, stream>>>(Xb, wdb, dense_b, (float*)d_out);
}

// Round 6
// 285.238 us; speedup vs baseline: 1.1011x; 1.0341x over previous
//
#include <hip/hip_runtime.h>

// MultiHeadedAttention B=8,S=1024,D=1024,H=16,dk=64 — bf16 MFMA pipeline.
// R10: GEMMs upgraded 2-phase -> 3-buffer ring, 2-deep prefetch, counted
// vmcnt (T4): per tile {WAITVM(6); s_barrier; compute(buf t); STG(t+2)}.
// Load slack = 2 full iterations (covers HBM ~900cyc); still ONE barrier
// per tile; vmcnt(0) only in the peeled last tile. LDS 144 KiB (3 x 48 KiB).
// R9 attention (exp2-fold, cvt_pk, permlane32_swap, T14 dbuf staging,
// XCD-friendly grid) unchanged. cvt/transp unchanged.

#define Sdim 1024
#define Ddim 1024

typedef unsigned short u16;
typedef float f32x4 __attribute__((ext_vector_type(4)));
typedef float f32x16 __attribute__((ext_vector_type(16)));
typedef __bf16 bf16x8 __attribute__((ext_vector_type(8)));
typedef u16 u16x8 __attribute__((ext_vector_type(8)));
typedef unsigned u32x2 __attribute__((ext_vector_type(2)));
typedef __attribute__((address_space(3))) void lds_void;
typedef __attribute__((address_space(1))) void gbl_void;

__device__ __forceinline__ u16 f2bf(float f) {
    unsigned u = __float_as_uint(f);
    u += 0x7fffu + ((u >> 16) & 1u);   // RNE
    return (u16)(u >> 16);
}
__device__ __forceinline__ void gld16(const void* g, void* l) {
    __builtin_amdgcn_global_load_lds((const gbl_void*)g, (lds_void*)l, 16, 0, 0);
}
__device__ __forceinline__ float fexp2(float x) {
#if __has_builtin(__builtin_amdgcn_exp2f)
    return __builtin_amdgcn_exp2f(x);
#else
    return __expf(x * 0.6931471805599453f);
#endif
}
// pack two f32 -> 2x bf16 (RNE) in one u32: v_cvt_pk_bf16_f32 (no builtin)
__device__ __forceinline__ unsigned cvtpk(float lo, float hi) {
    unsigned r;
    asm("v_cvt_pk_bf16_f32 %0, %1, %2" : "=v"(r) : "v"(lo), "v"(hi));
    return r;
}
#define MFMA16(a, b, c) __builtin_amdgcn_mfma_f32_16x16x32_bf16((a), (b), (c), 0, 0, 0)
#define MFMA32(a, b, c) __builtin_amdgcn_mfma_f32_32x32x16_bf16((a), (b), (c), 0, 0, 0)
#define SCHEDB() __builtin_amdgcn_sched_barrier(0)
#define SBAR() __builtin_amdgcn_s_barrier()
#define WAITVM(n) asm volatile("s_waitcnt vmcnt(" #n ")" ::: "memory")

#define QSCALE 0.18033688011112042f   // 0.125 * log2(e)

// ---------------------------------------------------------------------------
// fused fp32->bf16 converts; y=0..2 activations (8M), y=3..6 weights (1M).
// y==3 (wq) is scaled by 0.125*log2e (folds 1/sqrt(dk) AND exp->exp2).
// ---------------------------------------------------------------------------
__global__ __launch_bounds__(256) void cvt_all(const float* __restrict__ s0,
                                               const float* __restrict__ s1,
                                               const float* __restrict__ s2,
                                               const float* __restrict__ s3,
                                               const float* __restrict__ s4,
                                               const float* __restrict__ s5,
                                               const float* __restrict__ s6,
                                               u16* __restrict__ d0, u16* __restrict__ d1,
                                               u16* __restrict__ d2, u16* __restrict__ d3,
                                               u16* __restrict__ d4, u16* __restrict__ d5,
                                               u16* __restrict__ d6) {
    const int z = blockIdx.y;
    if (z >= 3 && blockIdx.x >= 512) return;
    const float* s = z == 0 ? s0 : z == 1 ? s1 : z == 2 ? s2 : z == 3 ? s3
                   : z == 4 ? s4 : z == 5 ? s5 : s6;
    u16* d = z == 0 ? d0 : z == 1 ? d1 : z == 2 ? d2 : z == 3 ? d3
           : z == 4 ? d4 : z == 5 ? d5 : d6;
    const float sc = (z == 3) ? QSCALE : 1.0f;
    const int i = (blockIdx.x * 256 + threadIdx.x) * 8;
    const float4 a = *(const float4*)(s + i);
    const float4 b = *(const float4*)(s + i + 4);
    u16x8 o;
    o[0] = f2bf(a.x * sc); o[1] = f2bf(a.y * sc); o[2] = f2bf(a.z * sc); o[3] = f2bf(a.w * sc);
    o[4] = f2bf(b.x * sc); o[5] = f2bf(b.y * sc); o[6] = f2bf(b.z * sc); o[7] = f2bf(b.w * sc);
    *(u16x8*)(d + i) = o;
}

// ---------------------------------------------------------------------------
// Deep-pipeline GEMM: C[M][1024] = A[M][1024] @ W[1024][1024]^T + bias*bscale
// Tile 256x128, BK=64, 512 thr = 8 waves (4Mx2N, wave owns 64x64).
// LDS 144 KiB: As[3][256][64 u16] @0 (3x32 KiB), Bs[3][128][64] @98304.
// Row r holds global row r; 16B chunk c stores global chunk c^(r&7) — XOR
// swizzle on ds_read addr, inverse on global_load_lds source (rule 21;
// SQ_LDS_BANK_CONFLICT == 0 verified R7-R9).
// Ring schedule (T4): prologue STG(0),STG(1); per tile t:
//   WAITVM(6)  [t<15; else 0]  -> own t-loads landed (t+1 stays in flight)
//   s_barrier                  -> ALL waves' t-loads landed; all waves past
//                                 compute(t-1), so buf (t-1)%3 is free
//   compute(t) on buf t%3
//   STG(t+2) into buf (t+2)%3 == (t-1)%3
// One barrier/tile; 2-iteration load slack covers HBM latency.
// ---------------------------------------------------------------------------
template <bool OUT_BF16>
__device__ __forceinline__ void gemm2p_body(const u16* __restrict__ A,
                                            const u16* __restrict__ W,
                                            const float* __restrict__ bias, float bscale,
                                            void* __restrict__ Cout,
                                            char* __restrict__ smem,
                                            int m0, int n0) {
    const int tid  = threadIdx.x;
    const int w    = tid >> 6;
    const int lane = tid & 63;
    const int l15  = lane & 15;
    const int quad = lane >> 4;
    const int wr   = w >> 1;          // 0..3 : 64-row block
    const int wc   = w & 1;           // 0..1 : 64-col block

    const int lrow = lane >> 3;                       // 0..7
    const int scol = (((lane & 7) ^ lrow) << 3);      // u16 units
    const u16* pa = A + (size_t)(m0 + w * 32 + lrow) * Ddim + scol;
    const u16* pb = W + (size_t)(n0 + w * 16 + lrow) * Ddim + scol;
    char* sAw = smem + w * 4096;                      // + buf*32768 + j*1024
    char* sBw = smem + 98304 + w * 2048;              // + buf*16384 + j*1024

#define STG(t, b)                                                             \
    do {                                                                      \
        const int k0 = (t) * 64;                                              \
        gld16(pa + k0,             sAw + (b) * 32768);                        \
        gld16(pa + k0 + 8 * 1024,  sAw + (b) * 32768 + 1024);                 \
        gld16(pa + k0 + 16 * 1024, sAw + (b) * 32768 + 2048);                 \
        gld16(pa + k0 + 24 * 1024, sAw + (b) * 32768 + 3072);                 \
        gld16(pb + k0,             sBw + (b) * 16384);                        \
        gld16(pb + k0 + 8 * 1024,  sBw + (b) * 16384 + 1024);                 \
    } while (0)

    const char* Ab = smem + (size_t)(wr * 64 + l15) * 128;
    const char* Bb = smem + 98304 + (size_t)(wc * 64 + l15) * 128;
    const int cx = ((quad ^ (l15 & 7)) << 4);

    f32x4 acc[4][4] = {};

    // prologue: 2-deep prefetch (12 loads outstanding)
    STG(0, 0);
    STG(1, 1);

    int cb = 0;   // current buffer
    for (int t = 0; t < 16; ++t) {
        if (t < 15) { WAITVM(6); } else { WAITVM(0); }
        SBAR();
        SCHEDB();   // keep ds_reads below the barrier
        const int boA = cb * 32768;
        const int boB = cb * 16384;
#pragma unroll
        for (int ks = 0; ks < 2; ++ks) {
            const int cxs = cx ^ (ks << 6);
            bf16x8 af[4], bfr[4];
#pragma unroll
            for (int i = 0; i < 4; ++i)
                af[i] = *(const bf16x8*)(Ab + boA + i * 2048 + cxs);
#pragma unroll
            for (int j = 0; j < 4; ++j)
                bfr[j] = *(const bf16x8*)(Bb + boB + j * 2048 + cxs);
#pragma unroll
            for (int i = 0; i < 4; ++i)
#pragma unroll
                for (int j = 0; j < 4; ++j)
                    acc[i][j] = MFMA16(af[i], bfr[j], acc[i][j]);
        }
        // stage t+2 into buf (t+2)%3 == (t-1)%3 (freed by this tile's barrier)
        int sb = cb + 2; if (sb >= 3) sb -= 3;
        if (t + 2 < 16) STG(t + 2, sb);
        cb = (cb + 1 == 3) ? 0 : cb + 1;
    }
#undef STG

    float bv[4];
#pragma unroll
    for (int j = 0; j < 4; ++j)
        bv[j] = bias[n0 + wc * 64 + j * 16 + l15] * bscale;
#pragma unroll
    for (int i = 0; i < 4; ++i)
#pragma unroll
        for (int j = 0; j < 4; ++j)
#pragma unroll
            for (int r = 0; r < 4; ++r) {
                const int row = m0 + wr * 64 + i * 16 + quad * 4 + r;
                const int col = n0 + wc * 64 + j * 16 + l15;
                const float v = acc[i][j][r] + bv[j];
                if (OUT_BF16)
                    ((u16*)Cout)[(size_t)row * Ddim + col] = f2bf(v);
                else
                    ((float*)Cout)[(size_t)row * Ddim + col] = v;
            }
}

__global__ __launch_bounds__(512, 2) void gemm2p_qkv(
        const u16* __restrict__ A0, const u16* __restrict__ A1, const u16* __restrict__ A2,
        const u16* __restrict__ W0, const u16* __restrict__ W1, const u16* __restrict__ W2,
        const float* __restrict__ b0, const float* __restrict__ b1, const float* __restrict__ b2,
        u16* __restrict__ C0, u16* __restrict__ C1, u16* __restrict__ C2) {
    __shared__ __align__(16) char smem[147456];
    const int d = blockIdx.x;
    const int s = (d & 7) * 96 + (d >> 3);
    const int z = s >> 8;
    const int rr = s & 255;
    const int tm = rr >> 3, tn = rr & 7;
    const u16* A = z == 0 ? A0 : z == 1 ? A1 : A2;
    const u16* W = z == 0 ? W0 : z == 1 ? W1 : W2;
    const float* bias = z == 0 ? b0 : z == 1 ? b1 : b2;
    u16* C = z == 0 ? C0 : z == 1 ? C1 : C2;
    const float bsc = (z == 0) ? QSCALE : 1.0f;   // wq path is pre-scaled
    gemm2p_body<true>(A, W, bias, bsc, (void*)C, smem, tm * 256, tn * 128);
}

__global__ __launch_bounds__(512, 2) void gemm2p_dense(const u16* __restrict__ A,
                                                       const u16* __restrict__ W,
                                                       const float* __restrict__ bias,
                                                       float* __restrict__ C) {
    __shared__ __align__(16) char smem[147456];
    const int d = blockIdx.x;
    const int s = (d & 7) * 32 + (d >> 3);
    const int tm = s >> 3, tn = s & 7;
    gemm2p_body<false>(A, W, bias, 1.0f, (void*)C, smem, tm * 256, tn * 128);
}

// ---------------------------------------------------------------------------
// V transpose: Vp[B*S][D] (bf16) -> Vt_g[(b*16+h)*64 + d][S]
// ---------------------------------------------------------------------------
__global__ __launch_bounds__(256) void transp_v(const u16* __restrict__ Vp,
                                                u16* __restrict__ Vt) {
    __shared__ __align__(16) u16 Ts[64][72];
    const int bh = blockIdx.x, s0 = blockIdx.y * 64;
    const int b = bh >> 4, h = bh & 15;
    const int tid = threadIdx.x;
#pragma unroll
    for (int p = 0; p < 2; ++p) {
        const int e = p * 2048 + tid * 8;
        const int r = e >> 6, c = e & 63;
        *(u16x8*)&Ts[r][c] =
            *(const u16x8*)(Vp + ((size_t)(b * Sdim + s0 + r)) * Ddim + h * 64 + c);
    }
    __syncthreads();
    const int d = tid >> 2, sp = tid & 3;
#pragma unroll
    for (int g = 0; g < 2; ++g) {
        u16x8 o;
#pragma unroll
        for (int j = 0; j < 8; ++j) o[j] = Ts[sp * 16 + g * 8 + j][d];
        *(u16x8*)(Vt + ((size_t)(bh * 64 + d)) * Sdim + s0 + sp * 16 + g * 8) = o;
    }
}

// ---------------------------------------------------------------------------
// Attention on 32x32 MFMA (R9). Grid (128 bh, 4 qblk). Block = 256 q-rows.
// p = exp2(S)*pol (wq pre-scaled 0.125*log2e); C->A via cvt_pk + permlane;
// K/V/pol double-buffered, T14 issue-early/write-late, ONE barrier per kt.
// ---------------------------------------------------------------------------
__global__ __launch_bounds__(256, 2) void attn_mfma(const u16* __restrict__ Qp,
                                                    const u16* __restrict__ Kp,
                                                    const u16* __restrict__ Vt,
                                                    const float* __restrict__ pol,
                                                    u16* __restrict__ Xb) {
    __shared__ __align__(16) u16 lds[37632];    // 75264 B
    u16* Qs = lds;                              // 256 x 72  (later: Xout)
    u16* Ks = lds + 18432;                      // 2 x 64 x 72   K[kpos][dk]
    u16* Vs = lds + 27648;                      // 2 x 64 x 72   V^T[d][kpos]
    float* pols = (float*)(lds + 36864);        // 2 x [64]
    float* denb = pols + 128;                   // [256] inv-den

    const int tid  = threadIdx.x;
    const int w    = tid >> 6;
    const int lane = tid & 63;
    const int l31  = lane & 31;
    const unsigned hsel = lane >> 5;            // half selector
    const int bh = blockIdx.x;
    const int q0 = blockIdx.y * 256;
    const size_t bS = (size_t)(bh >> 4) * Sdim;
    const int col0 = (bh & 15) * 64;
    const int sr = tid >> 2;                    // staging row 0..63
    const int sc4 = tid & 3;                    // staging chunk base

    const u16* Kg = Kp + (bS + sr) * Ddim + col0 + sc4 * 8;
    const u16* Vg = Vt + ((size_t)(bh * 64 + sr)) * Sdim + sc4 * 8;
    const float* pg = pol + bS + tid;

    // ---- stage Q tile 256x64, K/V/pol tile kt=0 into buf0 ----
#pragma unroll
    for (int rg = 0; rg < 4; ++rg) {
        const int r = rg * 64 + sr;
#pragma unroll
        for (int g = 0; g < 2; ++g) {
            const int ch = sc4 + g * 4;
            *(u16x8*)(Qs + r * 72 + ch * 8) =
                *(const u16x8*)(Qp + (bS + q0 + r) * Ddim + col0 + ch * 8);
        }
    }
#pragma unroll
    for (int g = 0; g < 2; ++g) {
        *(u16x8*)(Ks + sr * 72 + (sc4 + g * 4) * 8) = *(const u16x8*)(Kg + g * 32);
        *(u16x8*)(Vs + sr * 72 + (sc4 + g * 4) * 8) = *(const u16x8*)(Vg + g * 32);
    }
    if (tid < 64) pols[tid] = pg[0];
    __syncthreads();

    bf16x8 Qf[2][4];
#pragma unroll
    for (int qt = 0; qt < 2; ++qt)
#pragma unroll
        for (int dkt = 0; dkt < 4; ++dkt)
            Qf[qt][dkt] = *(const bf16x8*)(Qs + (w * 64 + qt * 32 + l31) * 72 +
                                           dkt * 16 + hsel * 8);

    f32x16 X[2][2] = {};
    float den[2] = {0.f, 0.f};

    for (int kt = 0; kt < 16; ++kt) {
        const int cur = kt & 1;
        const bool pf = (kt < 15);
        // ---- T14 issue-early: next tile's global loads into regs ----
        u16x8 kr0 = {}, kr1 = {}, vr0 = {}, vr1 = {};
        float polr = 0.f;
        if (pf) {
            const int ko = (kt + 1) * 64;
            kr0 = *(const u16x8*)(Kg + (size_t)ko * Ddim);
            kr1 = *(const u16x8*)(Kg + (size_t)ko * Ddim + 32);
            vr0 = *(const u16x8*)(Vg + ko);
            vr1 = *(const u16x8*)(Vg + ko + 32);
            if (tid < 64) polr = pg[ko];
        }
        SCHEDB();   // keep load issue above compute

        const u16* Ksc = Ks + cur * 4608;
        const u16* Vsc = Vs + cur * 4608;
        const float* polc = pols + cur * 64;
#pragma unroll
        for (int t32 = 0; t32 < 2; ++t32) {
            float polv[16];
#pragma unroll
            for (int e = 0; e < 16; ++e)
                polv[e] = polc[t32 * 32 + (e & 3) + 8 * (e >> 2) + 4 * hsel];
            bf16x8 Kf[4];
#pragma unroll
            for (int dkt = 0; dkt < 4; ++dkt)
                Kf[dkt] = *(const bf16x8*)(Ksc + (t32 * 32 + l31) * 72 +
                                           dkt * 16 + hsel * 8);
#pragma unroll
            for (int qt = 0; qt < 2; ++qt) {
                f32x16 S = {};
#pragma unroll
                for (int dkt = 0; dkt < 4; ++dkt)
                    S = MFMA32(Kf[dkt], Qf[qt][dkt], S);   // D[kpos][q]
                float p[16];
#pragma unroll
                for (int e = 0; e < 16; ++e) {
                    p[e] = fexp2(S[e]) * polv[e];
                    den[qt] += p[e];
                }
                unsigned pk_[8];
#pragma unroll
                for (int g = 0; g < 4; ++g) {
                    pk_[2 * g]     = cvtpk(p[4 * g + 0], p[4 * g + 1]);
                    pk_[2 * g + 1] = cvtpk(p[4 * g + 2], p[4 * g + 3]);
                }
#pragma unroll
                for (int tau = 0; tau < 2; ++tau) {
                    const u32x2 sA = __builtin_amdgcn_permlane32_swap(
                        pk_[4 * tau + 0], pk_[4 * tau + 2], false, false);
                    const u32x2 sB = __builtin_amdgcn_permlane32_swap(
                        pk_[4 * tau + 1], pk_[4 * tau + 3], false, false);
                    union { unsigned u[4]; bf16x8 v; } Af;
                    Af.u[0] = sA[0]; Af.u[1] = sB[0];
                    Af.u[2] = sA[1]; Af.u[3] = sB[1];
#pragma unroll
                    for (int ndt = 0; ndt < 2; ++ndt) {
                        const bf16x8 Vf =
                            *(const bf16x8*)(Vsc + (ndt * 32 + l31) * 72 +
                                             t32 * 32 + tau * 16 + hsel * 8);
                        X[qt][ndt] = MFMA32(Af.v, Vf, X[qt][ndt]);  // D[q][d]
                    }
                }
            }
        }
        // ---- T14 write-late: publish next tile into the other buffer ----
        if (pf) {
            const int nxt = cur ^ 1;
            *(u16x8*)(Ks + nxt * 4608 + sr * 72 + sc4 * 8) = kr0;
            *(u16x8*)(Ks + nxt * 4608 + sr * 72 + (sc4 + 4) * 8) = kr1;
            *(u16x8*)(Vs + nxt * 4608 + sr * 72 + sc4 * 8) = vr0;
            *(u16x8*)(Vs + nxt * 4608 + sr * 72 + (sc4 + 4) * 8) = vr1;
            if (tid < 64) pols[nxt * 64 + tid] = polr;
        }
        __syncthreads();
    }

    // ---- epilogue: den reduce, normalize, stage to LDS, coalesced store ----
#pragma unroll
    for (int qt = 0; qt < 2; ++qt) {
        den[qt] += __shfl_xor(den[qt], 32);
        denb[w * 64 + qt * 32 + l31] = 1.0f / (den[qt] + 1e-6f);
    }
    u16* Xout = Qs;   // Q frags live in regs; Qs region reused (barriers below)
#pragma unroll
    for (int qt = 0; qt < 2; ++qt) {
        float invv[16];
#pragma unroll
        for (int e = 0; e < 16; ++e)
            invv[e] = denb[w * 64 + qt * 32 + (e & 3) + 8 * (e >> 2) + 4 * hsel];
#pragma unroll
        for (int ndt = 0; ndt < 2; ++ndt)
#pragma unroll
            for (int e = 0; e < 16; ++e) {
                const int rho = (e & 3) + 8 * (e >> 2) + 4 * hsel;
                Xout[(w * 64 + qt * 32 + rho) * 72 + ndt * 32 + l31] =
                    f2bf(X[qt][ndt][e] * invv[e]);
            }
    }
    __syncthreads();
#pragma unroll
    for (int rg = 0; rg < 4; ++rg) {
        const int r = rg * 64 + sr;
#pragma unroll
        for (int g = 0; g < 2; ++g) {
            const int ch = sc4 + g * 4;
            *(u16x8*)(Xb + (bS + q0 + r) * Ddim + col0 + ch * 8) =
                *(const u16x8*)(Xout + r * 72 + ch * 8);
        }
    }
}

// ---------------------------------------------------------------------------
extern "C" void kernel_launch(void* const* d_in, const int* in_sizes, int n_in,
                              void* d_out, int out_size, void* d_ws, size_t ws_size,
                              hipStream_t stream) {
    const float* query   = (const float*)d_in[0];
    const float* key     = (const float*)d_in[1];
    const float* value   = (const float*)d_in[2];
    const float* policy  = (const float*)d_in[3];
    const float* wq_w    = (const float*)d_in[4];
    const float* wq_b    = (const float*)d_in[5];
    const float* wk_w    = (const float*)d_in[6];
    const float* wk_b    = (const float*)d_in[7];
    const float* wv_w    = (const float*)d_in[8];
    const float* wv_b    = (const float*)d_in[9];
    const float* dense_w = (const float*)d_in[10];
    const float* dense_b = (const float*)d_in[11];

    const size_t MM = 1u << 20;
    const size_t A8 = 8 * MM;
    u16* qa  = (u16*)d_ws;        // later aliased as Xb
    u16* ka  = qa + A8;           // later aliased as Vtg
    u16* va  = ka + A8;
    u16* wqb = va + A8;
    u16* wkb = wqb + MM;
    u16* wvb = wkb + MM;
    u16* wdb = wvb + MM;
    u16* Qp  = wdb + MM;
    u16* Kp  = Qp + A8;
    u16* Vp  = Kp + A8;
    u16* Vtg = ka;                // safe: ka consumed by gemm2p_qkv before transp_v
    u16* Xb  = qa;                // safe: qa consumed by gemm2p_qkv before attn

    cvt_all<<<dim3(4096, 7), 256, 0, stream>>>(query, key, value, wq_w, wk_w, wv_w, dense_w,
                                               qa, ka, va, wqb, wkb, wvb, wdb);

    gemm2p_qkv<<<dim3(768), 512, 0, stream>>>(qa, ka, va, wqb, wkb, wvb,
                                              wq_b, wk_b, wv_b, Qp, Kp, Vp);
    transp_v<<<dim3(128, 16), 256, 0, stream>>>(Vp, Vtg);

    attn_mfma<<<dim3(128, 4), 256, 0, stream>>>(Qp, Kp, Vtg, policy, Xb);

    gemm2p_dense<<<dim3(256), 512, 0, stream>>>(Xb, wdb, dense_b, (float*)d_out);
}